// Round 2
// baseline (1075.861 us; speedup 1.0000x reference)
//
#include <hip/hip_runtime.h>
#include <hip/hip_bf16.h>
#include <cstdint>
#include <cstddef>

#define TT 8192
#define DD 1024
#define II 4096
#define EE 8
#define CAP 2560

#define BM 128
#define BN 128
#define BK 32
#define LDK 40   // padded LDS row stride (bf16 elems): 80 B

typedef __attribute__((ext_vector_type(4))) float f32x4_t;
typedef __attribute__((ext_vector_type(8))) short bf16x8_t;

static __device__ __forceinline__ unsigned short f2bf(float f) {
    __hip_bfloat16 h = __float2bfloat16(f);
    return *reinterpret_cast<unsigned short*>(&h);
}
static __device__ __forceinline__ float geluf(float v) {
    return 0.5f * v * (1.0f + erff(v * 0.70710678118654752f));
}

// ---------------------------------------------------------------------------
// fp32 -> bf16 transposed copy: out[c*R + r] = bf16(in[r*C + c]), per batch z.
// ---------------------------------------------------------------------------
__global__ __launch_bounds__(256) void transpose_cvt(
    const float* __restrict__ in, unsigned short* __restrict__ out, int R, int C) {
    __shared__ float tile[32][33];
    size_t mb = (size_t)blockIdx.z * (size_t)R * (size_t)C;
    in += mb; out += mb;
    int cb = blockIdx.x * 32, rb = blockIdx.y * 32;
    int tx = threadIdx.x, ty = threadIdx.y;
#pragma unroll
    for (int j = 0; j < 4; ++j)
        tile[ty + j * 8][tx] = in[(size_t)(rb + ty + j * 8) * C + cb + tx];
    __syncthreads();
#pragma unroll
    for (int j = 0; j < 4; ++j)
        out[(size_t)(cb + ty + j * 8) * R + rb + tx] = f2bf(tile[tx][ty + j * 8]);
}

// ---------------------------------------------------------------------------
// Router: one wave per token. logits = x @ Wr^T; top-2; w0 = 1/(1+exp(l1-l0)).
// ---------------------------------------------------------------------------
__global__ __launch_bounds__(256) void router_kernel(
    const float* __restrict__ x, const float* __restrict__ Wr,
    int* __restrict__ e0a, int* __restrict__ e1a,
    float* __restrict__ w0a, float* __restrict__ w1a) {
    int t = blockIdx.x * 4 + (threadIdx.x >> 6);
    int lane = threadIdx.x & 63;
    const float* xr = x + (size_t)t * DD;
    float acc[EE];
#pragma unroll
    for (int e = 0; e < EE; ++e) acc[e] = 0.f;
    for (int c = 0; c < DD; c += 64) {
        float xv = xr[c + lane];
#pragma unroll
        for (int e = 0; e < EE; ++e) acc[e] += xv * Wr[e * DD + c + lane];
    }
#pragma unroll
    for (int e = 0; e < EE; ++e) {
        float v = acc[e];
#pragma unroll
        for (int off = 32; off > 0; off >>= 1) v += __shfl_xor(v, off, 64);
        acc[e] = v;
    }
    if (lane == 0) {
        int b0 = 0; float m0 = acc[0];
#pragma unroll
        for (int e = 1; e < EE; ++e) if (acc[e] > m0) { m0 = acc[e]; b0 = e; }
        int b1 = -1; float m1 = -3.4e38f;
#pragma unroll
        for (int e = 0; e < EE; ++e) if (e != b0 && acc[e] > m1) { m1 = acc[e]; b1 = e; }
        float w0 = 1.f / (1.f + expf(m1 - m0));
        e0a[t] = b0; e1a[t] = b1; w0a[t] = w0; w1a[t] = 1.f - w0;
    }
}

// ---------------------------------------------------------------------------
// Assignment: single block, 1024 threads, 8 tokens/thread (blocked, in token
// order). Sequentially over experts 0..7: eligibility (match & !fallback),
// block-wide prefix sum -> position, kept if pos<CAP else fallback. Mirrors
// the reference's cumulative-fallback semantics exactly. Afterwards: pad slot
// lists, zero weights of tokens that ended up fallback, build fallback list.
// ---------------------------------------------------------------------------
__global__ __launch_bounds__(1024) void assign_kernel(
    const int* __restrict__ e0a, const int* __restrict__ e1a,
    const float* __restrict__ w0a, const float* __restrict__ w1a,
    int* __restrict__ idxb, float* __restrict__ wslb,
    int* __restrict__ fbidx, int* __restrict__ counts) {
    __shared__ int sc[1024];
    __shared__ int ns[EE];
    const int t = threadIdx.x;
    int e0v[8], e1v[8]; float w0v[8], w1v[8];
    bool fbv[8]; int sA[8], sB[8];
#pragma unroll
    for (int j = 0; j < 8; ++j) {
        int tok = t * 8 + j;
        e0v[j] = e0a[tok]; e1v[j] = e1a[tok];
        w0v[j] = w0a[tok]; w1v[j] = w1a[tok];
        fbv[j] = false; sA[j] = -1; sB[j] = -1;
    }
    for (int e = 0; e < EE; ++e) {
        int lp[8]; int c = 0; bool el[8];
#pragma unroll
        for (int j = 0; j < 8; ++j) {
            el[j] = (!fbv[j]) && (e0v[j] == e || e1v[j] == e);
            lp[j] = c; c += el[j] ? 1 : 0;
        }
        sc[t] = c; __syncthreads();
        for (int off = 1; off < 1024; off <<= 1) {
            int add = (t >= off) ? sc[t - off] : 0;
            __syncthreads();
            sc[t] += add;
            __syncthreads();
        }
        int base = sc[t] - c;
        int total = sc[1023];
#pragma unroll
        for (int j = 0; j < 8; ++j) {
            if (el[j]) {
                int pos = base + lp[j];
                if (pos < CAP) {
                    int s = e * CAP + pos;
                    idxb[s] = t * 8 + j;
                    wslb[s] = (e0v[j] == e) ? w0v[j] : w1v[j];
                    if (sA[j] < 0) sA[j] = s; else sB[j] = s;
                } else {
                    fbv[j] = true;
                }
            }
        }
        if (t == 0) ns[e] = total < CAP ? total : CAP;
        __syncthreads();
    }
    // pad unused slots (safe gather target token 0, weight 0)
    for (int s = t; s < EE * CAP; s += 1024) {
        int e = s / CAP, pos = s - e * CAP;
        if (pos >= ns[e]) { idxb[s] = 0; wslb[s] = 0.f; }
    }
    // tokens that fell back: zero their kept-slot weights (earlier expert's
    // contribution must be discarded, per reference overwrite semantics)
#pragma unroll
    for (int j = 0; j < 8; ++j) {
        if (fbv[j]) {
            if (sA[j] >= 0) wslb[sA[j]] = 0.f;
            if (sB[j] >= 0) wslb[sB[j]] = 0.f;
        }
    }
    // compact fallback token list
    int lp[8]; int c = 0;
#pragma unroll
    for (int j = 0; j < 8; ++j) { lp[j] = c; c += fbv[j] ? 1 : 0; }
    sc[t] = c; __syncthreads();
    for (int off = 1; off < 1024; off <<= 1) {
        int add = (t >= off) ? sc[t - off] : 0;
        __syncthreads();
        sc[t] += add;
        __syncthreads();
    }
    int base = sc[t] - c;
    int total = sc[1023];
#pragma unroll
    for (int j = 0; j < 8; ++j)
        if (fbv[j]) fbidx[base + lp[j]] = t * 8 + j;
    for (int s = t; s < TT; s += 1024)
        if (s >= total) fbidx[s] = 0;
    if (t == 0) {
        for (int e = 0; e < EE; ++e) counts[e] = ns[e];
        counts[EE] = total;
    }
}

// ---------------------------------------------------------------------------
// GEMM core, bf16 MFMA 16x16x32, 128x128 tile, BK=32, 256 threads (2x2 waves,
// 64x64 per wave = 4x4 MFMA tiles). B stored transposed ([n][k]) so both LDS
// fragments are contiguous-k reads. ONE mfma per (i,j) per k-tile: the
// instruction consumes all K=32 (lane quad holds k=quad*8+j).
// MODE 0: expert GEMM1  A = gather x (fp32->bf16) via idx, out H = gelu(.+b1)
// MODE 1: expert GEMM2  A = H, out: atomicAdd d_out[tok] += (.+b2)*w
// MODE 2: fallback GEMM1 (gather via fbidx+chunk)
// MODE 3: fallback GEMM2 (store d_out[tok] = .+fb2, masked by n_fb)
// ---------------------------------------------------------------------------
template <int MODE>
__global__ __launch_bounds__(256) void gemm_kernel(
    const float* __restrict__ xsrc,
    const unsigned short* __restrict__ Asrc,
    const unsigned short* __restrict__ Bt,
    const float* __restrict__ bias,
    unsigned short* __restrict__ Hout,
    float* __restrict__ dout,
    const int* __restrict__ idxp,
    const float* __restrict__ wslp,
    const int* __restrict__ counts,
    int e_base, int chunk_base) {
    constexpr bool IS_G1 = (MODE == 0 || MODE == 2);
    constexpr bool IS_EXPERT = (MODE == 0 || MODE == 1);
    constexpr int K = IS_G1 ? DD : II;

    const int z = blockIdx.z;
    const int e = e_base + z;
    const int m_base = blockIdx.x * BM;   // slot within expert / chunk-local
    const int n_base = blockIdx.y * BN;

    const int cnt = IS_EXPERT ? counts[e] : counts[EE];
    if (IS_EXPERT) { if (m_base >= cnt) return; }
    else           { if (chunk_base + m_base >= cnt) return; }

    __shared__ alignas(16) unsigned short As[BM * LDK];
    __shared__ alignas(16) unsigned short Bs[BN * LDK];

    const int tid = threadIdx.x;
    const int lane = tid & 63;
    const int wv = tid >> 6;
    const int wm = (wv & 1) * 64;
    const int wn = (wv >> 1) * 64;
    const int l15 = lane & 15;
    const int quad = lane >> 4;

    const unsigned short* BtE;
    if (MODE == 0)      BtE = Bt + (size_t)e * II * DD;
    else if (MODE == 1) BtE = Bt + (size_t)e * DD * II;
    else                BtE = Bt;

    const int ar  = tid >> 3;        // G1: 32 rows/pass, 8 thr/row
    const int ac  = (tid & 7) * 4;   // float offset
    const int ar2 = tid >> 2;        // bf16: 64 rows/pass, 4 thr/row
    const int ac2 = (tid & 3) * 8;   // elem offset

    const float* aptr[4];
    const unsigned short* aptr2[2];
    if (IS_G1) {
#pragma unroll
        for (int p = 0; p < 4; ++p) {
            int slot = m_base + p * 32 + ar;
            int tok = (MODE == 0) ? idxp[e * CAP + slot] : idxp[chunk_base + slot];
            aptr[p] = xsrc + (size_t)tok * DD + ac;
        }
    } else {
        const unsigned short* Ab = (MODE == 1) ? (Asrc + (size_t)z * CAP * II) : Asrc;
#pragma unroll
        for (int p = 0; p < 2; ++p)
            aptr2[p] = Ab + (size_t)(m_base + p * 64 + ar2) * II + ac2;
    }

    f32x4_t acc[4][4];
#pragma unroll
    for (int i = 0; i < 4; ++i)
#pragma unroll
        for (int j = 0; j < 4; ++j) acc[i][j] = (f32x4_t){0.f, 0.f, 0.f, 0.f};

    for (int k0 = 0; k0 < K; k0 += BK) {
        if (IS_G1) {
#pragma unroll
            for (int p = 0; p < 4; ++p) {
                int row = p * 32 + ar;
                float4 v = *(const float4*)(aptr[p] + k0);
                unsigned long long pk =
                      (unsigned long long)f2bf(v.x)
                    | ((unsigned long long)f2bf(v.y) << 16)
                    | ((unsigned long long)f2bf(v.z) << 32)
                    | ((unsigned long long)f2bf(v.w) << 48);
                *(unsigned long long*)&As[row * LDK + ac] = pk;
            }
        } else {
#pragma unroll
            for (int p = 0; p < 2; ++p) {
                int row = p * 64 + ar2;
                uint4 v = *(const uint4*)(aptr2[p] + k0);
                *(uint4*)&As[row * LDK + ac2] = v;
            }
        }
#pragma unroll
        for (int p = 0; p < 2; ++p) {
            int n = p * 64 + ar2;
            uint4 v = *(const uint4*)(BtE + (size_t)(n_base + n) * K + k0 + ac2);
            *(uint4*)&Bs[n * LDK + ac2] = v;
        }
        __syncthreads();
        {
            const int koff = quad * 8;   // lane quad holds k = quad*8 + j, j in [0,8)
            bf16x8_t af[4], bfv[4];
#pragma unroll
            for (int i = 0; i < 4; ++i)
                af[i] = *(const bf16x8_t*)&As[(wm + i * 16 + l15) * LDK + koff];
#pragma unroll
            for (int j = 0; j < 4; ++j)
                bfv[j] = *(const bf16x8_t*)&Bs[(wn + j * 16 + l15) * LDK + koff];
#pragma unroll
            for (int i = 0; i < 4; ++i)
#pragma unroll
                for (int j = 0; j < 4; ++j)
                    acc[i][j] = __builtin_amdgcn_mfma_f32_16x16x32_bf16(
                        af[i], bfv[j], acc[i][j], 0, 0, 0);
        }
        __syncthreads();
    }

    // epilogue: C/D layout row = quad*4 + reg, col = lane&15 (verified m89/m91)
#pragma unroll
    for (int i = 0; i < 4; ++i) {
        const int mrow0 = wm + i * 16 + quad * 4;
#pragma unroll
        for (int j = 0; j < 4; ++j) {
            const int ncol = n_base + wn + j * 16 + l15;
            float bv;
            if (MODE == 0)      bv = bias[(size_t)e * II + ncol];
            else if (MODE == 1) bv = bias[(size_t)e * DD + ncol];
            else                bv = bias[ncol];
#pragma unroll
            for (int r = 0; r < 4; ++r) {
                const int slot = m_base + mrow0 + r;
                float v = acc[i][j][r] + bv;
                if (MODE == 0) {
                    Hout[(size_t)(z * CAP + slot) * II + ncol] = f2bf(geluf(v));
                } else if (MODE == 2) {
                    Hout[(size_t)slot * II + ncol] = f2bf(geluf(v));
                } else if (MODE == 1) {
                    float w = wslp[e * CAP + slot];
                    if (w != 0.f) {
                        int tok = idxp[e * CAP + slot];
                        atomicAdd(&dout[(size_t)tok * DD + ncol], v * w);
                    }
                } else { // MODE == 3
                    int rg = chunk_base + slot;
                    if (rg < cnt) {
                        int tok = idxp[rg];
                        dout[(size_t)tok * DD + ncol] = v;
                    }
                }
            }
        }
    }
}

// ---------------------------------------------------------------------------
extern "C" void kernel_launch(void* const* d_in, const int* in_sizes, int n_in,
                              void* d_out, int out_size, void* d_ws, size_t ws_size,
                              hipStream_t stream) {
    const float* x   = (const float*)d_in[0];
    const float* Wr  = (const float*)d_in[1];
    const float* W1  = (const float*)d_in[2];
    const float* b1  = (const float*)d_in[3];
    const float* W2  = (const float*)d_in[4];
    const float* b2  = (const float*)d_in[5];
    const float* fw1 = (const float*)d_in[6];
    const float* fb1 = (const float*)d_in[7];
    const float* fw2 = (const float*)d_in[8];
    const float* fb2 = (const float*)d_in[9];
    float* out = (float*)d_out;

    char* ws = (char*)d_ws;
    size_t off = 0;
    auto alloc = [&](size_t bytes) -> void* {
        void* p = ws + off;
        off += (bytes + 255) & ~(size_t)255;
        return p;
    };
    unsigned short* W1t  = (unsigned short*)alloc((size_t)EE * DD * II * 2);
    unsigned short* W2t  = (unsigned short*)alloc((size_t)EE * II * DD * 2);
    unsigned short* fw1t = (unsigned short*)alloc((size_t)DD * II * 2);
    unsigned short* fw2t = (unsigned short*)alloc((size_t)II * DD * 2);
    int*   e0a   = (int*)alloc(TT * 4);
    int*   e1a   = (int*)alloc(TT * 4);
    float* w0a   = (float*)alloc(TT * 4);
    float* w1a   = (float*)alloc(TT * 4);
    int*   idxb  = (int*)alloc(EE * CAP * 4);
    float* wslb  = (float*)alloc(EE * CAP * 4);
    int*   fbidx = (int*)alloc(TT * 4);
    int*   counts = (int*)alloc(64);

    // H buffer: as many experts' worth as workspace allows (21 MB each)
    size_t perExpert = (size_t)CAP * II * 2;
    size_t remain = (ws_size > off) ? (ws_size - off) : 0;
    int G = (int)(remain / perExpert);
    if (G < 1) G = 1;
    if (G > EE) G = EE;
    unsigned short* H = (unsigned short*)(ws + off);

    hipMemsetAsync(d_out, 0, (size_t)TT * DD * sizeof(float), stream);

    // weight conversion + transpose (B^T layouts)
    transpose_cvt<<<dim3(II / 32, DD / 32, EE), dim3(32, 8), 0, stream>>>(W1, W1t, DD, II);
    transpose_cvt<<<dim3(DD / 32, II / 32, EE), dim3(32, 8), 0, stream>>>(W2, W2t, II, DD);
    transpose_cvt<<<dim3(II / 32, DD / 32, 1),  dim3(32, 8), 0, stream>>>(fw1, fw1t, DD, II);
    transpose_cvt<<<dim3(DD / 32, II / 32, 1),  dim3(32, 8), 0, stream>>>(fw2, fw2t, II, DD);

    router_kernel<<<TT / 4, 256, 0, stream>>>(x, Wr, e0a, e1a, w0a, w1a);
    assign_kernel<<<1, 1024, 0, stream>>>(e0a, e1a, w0a, w1a, idxb, wslb, fbidx, counts);

    for (int eb = 0; eb < EE; eb += G) {
        int g = (EE - eb < G) ? (EE - eb) : G;
        gemm_kernel<0><<<dim3(CAP / BM, II / BN, g), 256, 0, stream>>>(
            x, nullptr, W1t, b1, H, nullptr, idxb, wslb, counts, eb, 0);
        gemm_kernel<1><<<dim3(CAP / BM, DD / BN, g), 256, 0, stream>>>(
            nullptr, H, W2t, b2, nullptr, out, idxb, wslb, counts, eb, 0);
    }
    // fallback FFN over overflow tokens only, in chunks of CAP rows (reuses H)
    for (int c = 0; c < 4; ++c) {
        gemm_kernel<2><<<dim3(CAP / BM, II / BN, 1), 256, 0, stream>>>(
            x, nullptr, fw1t, fb1, H, nullptr, fbidx, nullptr, counts, 0, c * CAP);
        gemm_kernel<3><<<dim3(CAP / BM, DD / BN, 1), 256, 0, stream>>>(
            nullptr, H, fw2t, fb2, nullptr, out, fbidx, nullptr, counts, 0, c * CAP);
    }
    (void)in_sizes; (void)n_in; (void)out_size;
}

// Round 3
// 955.636 us; speedup vs baseline: 1.1258x; 1.1258x over previous
//
#include <hip/hip_runtime.h>
#include <hip/hip_bf16.h>
#include <cstdint>
#include <cstddef>

#define TT 8192
#define DD 1024
#define II 4096
#define EE 8
#define CAP 2560

#define BM 128
#define BN 128
#define BK 32   // bf16 elems per k-tile; row = 64 B, unpadded (global_load_lds layout)

typedef __attribute__((ext_vector_type(4))) float f32x4_t;
typedef __attribute__((ext_vector_type(8))) short bf16x8_t;

static __device__ __forceinline__ unsigned short f2bf(float f) {
    __hip_bfloat16 h = __float2bfloat16(f);
    return *reinterpret_cast<unsigned short*>(&h);
}
static __device__ __forceinline__ float geluf(float v) {
    return 0.5f * v * (1.0f + erff(v * 0.70710678118654752f));
}

// async global->LDS, 16 B per lane; LDS dest = wave-uniform base + lane*16.
static __device__ __forceinline__ void gl_lds16(const void* g, void* l) {
    __builtin_amdgcn_global_load_lds(
        (__attribute__((address_space(1))) unsigned int*)g,
        (__attribute__((address_space(3))) unsigned int*)l, 16, 0, 0);
}

// ---------------------------------------------------------------------------
// fp32 -> bf16 flat convert (for x): 8 elems/thread.
// ---------------------------------------------------------------------------
__global__ __launch_bounds__(256) void cvt_x(
    const float* __restrict__ in, unsigned short* __restrict__ out) {
    int i = (blockIdx.x * 256 + threadIdx.x) * 8;
    float4 a = *(const float4*)(in + i);
    float4 b = *(const float4*)(in + i + 4);
    union { unsigned short s[8]; uint4 u; } pk;
    pk.s[0] = f2bf(a.x); pk.s[1] = f2bf(a.y); pk.s[2] = f2bf(a.z); pk.s[3] = f2bf(a.w);
    pk.s[4] = f2bf(b.x); pk.s[5] = f2bf(b.y); pk.s[6] = f2bf(b.z); pk.s[7] = f2bf(b.w);
    *(uint4*)(out + i) = pk.u;
}

// ---------------------------------------------------------------------------
// fp32 -> bf16 transposed copy: out[c*R + r] = bf16(in[r*C + c]), per batch z.
// ---------------------------------------------------------------------------
__global__ __launch_bounds__(256) void transpose_cvt(
    const float* __restrict__ in, unsigned short* __restrict__ out, int R, int C) {
    __shared__ float tile[32][33];
    size_t mb = (size_t)blockIdx.z * (size_t)R * (size_t)C;
    in += mb; out += mb;
    int cb = blockIdx.x * 32, rb = blockIdx.y * 32;
    int tx = threadIdx.x, ty = threadIdx.y;
#pragma unroll
    for (int j = 0; j < 4; ++j)
        tile[ty + j * 8][tx] = in[(size_t)(rb + ty + j * 8) * C + cb + tx];
    __syncthreads();
#pragma unroll
    for (int j = 0; j < 4; ++j)
        out[(size_t)(cb + ty + j * 8) * R + rb + tx] = f2bf(tile[tx][ty + j * 8]);
}

// ---------------------------------------------------------------------------
// Router: one wave per token. top-2; w0 = 1/(1+exp(l1-l0)) (= renorm softmax).
// ---------------------------------------------------------------------------
__global__ __launch_bounds__(256) void router_kernel(
    const float* __restrict__ x, const float* __restrict__ Wr,
    int* __restrict__ e0a, int* __restrict__ e1a,
    float* __restrict__ w0a, float* __restrict__ w1a) {
    int t = blockIdx.x * 4 + (threadIdx.x >> 6);
    int lane = threadIdx.x & 63;
    const float* xr = x + (size_t)t * DD;
    float acc[EE];
#pragma unroll
    for (int e = 0; e < EE; ++e) acc[e] = 0.f;
    for (int c = 0; c < DD; c += 64) {
        float xv = xr[c + lane];
#pragma unroll
        for (int e = 0; e < EE; ++e) acc[e] += xv * Wr[e * DD + c + lane];
    }
#pragma unroll
    for (int e = 0; e < EE; ++e) {
        float v = acc[e];
#pragma unroll
        for (int off = 32; off > 0; off >>= 1) v += __shfl_xor(v, off, 64);
        acc[e] = v;
    }
    if (lane == 0) {
        int b0 = 0; float m0 = acc[0];
#pragma unroll
        for (int e = 1; e < EE; ++e) if (acc[e] > m0) { m0 = acc[e]; b0 = e; }
        int b1 = -1; float m1 = -3.4e38f;
#pragma unroll
        for (int e = 0; e < EE; ++e) if (e != b0 && acc[e] > m1) { m1 = acc[e]; b1 = e; }
        float w0 = 1.f / (1.f + expf(m1 - m0));
        e0a[t] = b0; e1a[t] = b1; w0a[t] = w0; w1a[t] = 1.f - w0;
    }
}

// ---------------------------------------------------------------------------
// Assignment: single block, 1024 threads (16 waves), 8 tokens/thread (token
// order). Per expert: eligibility, block scan (wave shfl scan + wave-sum scan,
// 2 barriers), kept if pos<CAP else fallback. Mirrors reference semantics.
// ---------------------------------------------------------------------------
__global__ __launch_bounds__(1024) void assign_kernel(
    const int* __restrict__ e0a, const int* __restrict__ e1a,
    const float* __restrict__ w0a, const float* __restrict__ w1a,
    int* __restrict__ idxb, float* __restrict__ wslb,
    int* __restrict__ fbidx, int* __restrict__ counts) {
    __shared__ int wsum[16];
    __shared__ int ns[EE];
    const int t = threadIdx.x;
    const int lane = t & 63;
    const int wv = t >> 6;
    int e0v[8], e1v[8]; float w0v[8], w1v[8];
    bool fbv[8]; int sA[8], sB[8];
#pragma unroll
    for (int j = 0; j < 8; ++j) {
        int tok = t * 8 + j;
        e0v[j] = e0a[tok]; e1v[j] = e1a[tok];
        w0v[j] = w0a[tok]; w1v[j] = w1a[tok];
        fbv[j] = false; sA[j] = -1; sB[j] = -1;
    }
    for (int e = 0; e < EE; ++e) {
        int lp[8]; int c = 0; bool el[8];
#pragma unroll
        for (int j = 0; j < 8; ++j) {
            el[j] = (!fbv[j]) && (e0v[j] == e || e1v[j] == e);
            lp[j] = c; c += el[j] ? 1 : 0;
        }
        int incl = c;
#pragma unroll
        for (int off = 1; off < 64; off <<= 1) {
            int v = __shfl_up(incl, off, 64);
            if (lane >= off) incl += v;
        }
        if (lane == 63) wsum[wv] = incl;
        __syncthreads();
        int wbase = 0, total = 0;
#pragma unroll
        for (int u = 0; u < 16; ++u) {
            int v = wsum[u];
            total += v;
            if (u < wv) wbase += v;
        }
        int base = wbase + incl - c;
#pragma unroll
        for (int j = 0; j < 8; ++j) {
            if (el[j]) {
                int pos = base + lp[j];
                if (pos < CAP) {
                    int s = e * CAP + pos;
                    idxb[s] = t * 8 + j;
                    wslb[s] = (e0v[j] == e) ? w0v[j] : w1v[j];
                    if (sA[j] < 0) sA[j] = s; else sB[j] = s;
                } else {
                    fbv[j] = true;
                }
            }
        }
        if (t == 0) ns[e] = total < CAP ? total : CAP;
        __syncthreads();   // protects wsum reuse + publishes ns[e]
    }
    // pad unused slots (safe gather target token 0, weight 0)
    for (int s = t; s < EE * CAP; s += 1024) {
        int e = s / CAP, pos = s - e * CAP;
        if (pos >= ns[e]) { idxb[s] = 0; wslb[s] = 0.f; }
    }
    // tokens that fell back: zero their kept-slot weights
#pragma unroll
    for (int j = 0; j < 8; ++j) {
        if (fbv[j]) {
            if (sA[j] >= 0) wslb[sA[j]] = 0.f;
            if (sB[j] >= 0) wslb[sB[j]] = 0.f;
        }
    }
    // compact fallback token list
    int lp[8]; int c = 0;
#pragma unroll
    for (int j = 0; j < 8; ++j) { lp[j] = c; c += fbv[j] ? 1 : 0; }
    int incl = c;
#pragma unroll
    for (int off = 1; off < 64; off <<= 1) {
        int v = __shfl_up(incl, off, 64);
        if (lane >= off) incl += v;
    }
    if (lane == 63) wsum[wv] = incl;
    __syncthreads();
    int wbase = 0, total = 0;
#pragma unroll
    for (int u = 0; u < 16; ++u) {
        int v = wsum[u];
        total += v;
        if (u < wv) wbase += v;
    }
    int base = wbase + incl - c;
#pragma unroll
    for (int j = 0; j < 8; ++j)
        if (fbv[j]) fbidx[base + lp[j]] = t * 8 + j;
    for (int s = t; s < 4 * CAP; s += 1024)   // padded to 4*CAP (gather-safe)
        if (s >= total) fbidx[s] = 0;
    if (t == 0) {
        for (int e = 0; e < EE; ++e) counts[e] = ns[e];
        counts[EE] = total;
    }
}

// ---------------------------------------------------------------------------
// GEMM core: bf16 MFMA 16x16x32, 128x128 tile, BK=32, 256 threads (2x2 waves,
// 64x64/wave). A and B staged via global_load_lds (16 B/lane, per-lane gather
// addresses). LDS rows are 64 B, k-chunk XOR-swizzled: LDS(row, pos) holds
// global k-chunk pos^((row>>2)&3), so b128 fragment reads hit 8 distinct
// start banks/quad (min-cycle, conflict-free).
// MODE 0: expert GEMM1 (A = x_bf gathered via idxb) -> H = gelu(.+b1)
// MODE 1: expert GEMM2 (A = H) -> atomicAdd d_out += (.+b2)*w
// MODE 2: fallback GEMM1 (A = x_bf gathered via fbidx, chunk = z)
// MODE 3: fallback GEMM2 (A = H chunk z) -> d_out[tok] = .+fb2
// ---------------------------------------------------------------------------
template <int MODE>
__global__ __launch_bounds__(256) void gemm_kernel(
    const unsigned short* __restrict__ Abase,
    const unsigned short* __restrict__ Bt,
    const float* __restrict__ bias,
    unsigned short* __restrict__ Hout,
    float* __restrict__ dout,
    const int* __restrict__ idxp,
    const float* __restrict__ wslp,
    const int* __restrict__ counts,
    int e_base, int chunk_base) {
    constexpr bool IS_G1 = (MODE == 0 || MODE == 2);
    constexpr bool IS_EXPERT = (MODE == 0 || MODE == 1);
    constexpr int K = IS_G1 ? DD : II;

    const int z = blockIdx.z;
    const int e = e_base + z;               // expert modes
    const int ch0 = chunk_base + z * CAP;   // fallback modes
    const int m_base = blockIdx.x * BM;
    const int n_base = blockIdx.y * BN;

    const int cnt = IS_EXPERT ? counts[e] : counts[EE];
    if (IS_EXPERT) { if (m_base >= cnt) return; }
    else           { if (ch0 + m_base >= cnt) return; }

    __shared__ alignas(16) unsigned short As[BM * BK];
    __shared__ alignas(16) unsigned short Bs[BN * BK];

    const int tid = threadIdx.x;
    const int lane = tid & 63;
    const int wv = tid >> 6;
    const int wm = (wv & 1) * 64;
    const int wn = (wv >> 1) * 64;
    const int l15 = lane & 15;
    const int quad = lane >> 4;

    const unsigned short* BtE;
    if (MODE == 0)      BtE = Bt + (size_t)e * II * DD;
    else if (MODE == 1) BtE = Bt + (size_t)e * DD * II;
    else                BtE = Bt;

    // staging lane geometry: 16 rows x 64 B per wave-instruction
    const int lrow = lane >> 2;                        // tile row within 16
    const int kc = (lane & 3) ^ ((lrow >> 2) & 3);     // swizzled global k-chunk
    const unsigned short* aP[2];
    const unsigned short* bP[2];
#pragma unroll
    for (int p = 0; p < 2; ++p) {
        int r = wv * 32 + p * 16 + lrow;   // 0..127
        int slot = m_base + r;
        int arow;
        if (MODE == 0)      arow = idxp[e * CAP + slot];
        else if (MODE == 2) arow = idxp[ch0 + slot];
        else                arow = z * CAP + slot;     // H rows
        aP[p] = Abase + (size_t)arow * K + kc * 8;
        int nrow = n_base + r;
        bP[p] = BtE + (size_t)nrow * K + kc * 8;
    }
    unsigned short* lA[2]; unsigned short* lB[2];
#pragma unroll
    for (int p = 0; p < 2; ++p) {
        lA[p] = &As[(wv * 32 + p * 16) * BK];
        lB[p] = &Bs[(wv * 32 + p * 16) * BK];
    }

    f32x4_t acc[4][4];
#pragma unroll
    for (int i = 0; i < 4; ++i)
#pragma unroll
        for (int j = 0; j < 4; ++j) acc[i][j] = (f32x4_t){0.f, 0.f, 0.f, 0.f};

    const int sw = (l15 >> 2) & 3;
    for (int k0 = 0; k0 < K; k0 += BK) {
        gl_lds16(aP[0], lA[0]); gl_lds16(aP[1], lA[1]);
        gl_lds16(bP[0], lB[0]); gl_lds16(bP[1], lB[1]);
        aP[0] += BK; aP[1] += BK; bP[0] += BK; bP[1] += BK;
        __syncthreads();
        bf16x8_t af[4], bfv[4];
#pragma unroll
        for (int i = 0; i < 4; ++i)
            af[i] = *(const bf16x8_t*)&As[(wm + i * 16 + l15) * BK + ((quad ^ sw) * 8)];
#pragma unroll
        for (int j = 0; j < 4; ++j)
            bfv[j] = *(const bf16x8_t*)&Bs[(wn + j * 16 + l15) * BK + ((quad ^ sw) * 8)];
#pragma unroll
        for (int i = 0; i < 4; ++i)
#pragma unroll
            for (int j = 0; j < 4; ++j)
                acc[i][j] = __builtin_amdgcn_mfma_f32_16x16x32_bf16(
                    af[i], bfv[j], acc[i][j], 0, 0, 0);
        __syncthreads();
    }

    // epilogue: C/D layout row = quad*4 + reg, col = lane&15
#pragma unroll
    for (int i = 0; i < 4; ++i) {
        const int mrow0 = wm + i * 16 + quad * 4;
#pragma unroll
        for (int j = 0; j < 4; ++j) {
            const int ncol = n_base + wn + j * 16 + l15;
            float bv;
            if (MODE == 0)      bv = bias[(size_t)e * II + ncol];
            else if (MODE == 1) bv = bias[(size_t)e * DD + ncol];
            else                bv = bias[ncol];
#pragma unroll
            for (int r = 0; r < 4; ++r) {
                const int slot = m_base + mrow0 + r;
                float v = acc[i][j][r] + bv;
                if (MODE == 0 || MODE == 2) {
                    Hout[(size_t)(z * CAP + slot) * II + ncol] = f2bf(geluf(v));
                } else if (MODE == 1) {
                    float w = wslp[e * CAP + slot];
                    if (w != 0.f) {
                        int tok = idxp[e * CAP + slot];
                        atomicAdd(&dout[(size_t)tok * DD + ncol], v * w);
                    }
                } else { // MODE == 3
                    int rg = ch0 + slot;
                    if (rg < cnt) {
                        int tok = idxp[rg];
                        dout[(size_t)tok * DD + ncol] = v;
                    }
                }
            }
        }
    }
}

// ---------------------------------------------------------------------------
extern "C" void kernel_launch(void* const* d_in, const int* in_sizes, int n_in,
                              void* d_out, int out_size, void* d_ws, size_t ws_size,
                              hipStream_t stream) {
    const float* x   = (const float*)d_in[0];
    const float* Wr  = (const float*)d_in[1];
    const float* W1  = (const float*)d_in[2];
    const float* b1  = (const float*)d_in[3];
    const float* W2  = (const float*)d_in[4];
    const float* b2  = (const float*)d_in[5];
    const float* fw1 = (const float*)d_in[6];
    const float* fb1 = (const float*)d_in[7];
    const float* fw2 = (const float*)d_in[8];
    const float* fb2 = (const float*)d_in[9];
    float* out = (float*)d_out;

    char* ws = (char*)d_ws;
    size_t off = 0;
    auto alloc = [&](size_t bytes) -> void* {
        void* p = ws + off;
        off += (bytes + 255) & ~(size_t)255;
        return p;
    };
    unsigned short* W1t  = (unsigned short*)alloc((size_t)EE * DD * II * 2);
    unsigned short* W2t  = (unsigned short*)alloc((size_t)EE * II * DD * 2);
    unsigned short* fw1t = (unsigned short*)alloc((size_t)DD * II * 2);
    unsigned short* fw2t = (unsigned short*)alloc((size_t)II * DD * 2);
    unsigned short* xbf  = (unsigned short*)alloc((size_t)TT * DD * 2);
    int*   e0a   = (int*)alloc(TT * 4);
    int*   e1a   = (int*)alloc(TT * 4);
    float* w0a   = (float*)alloc(TT * 4);
    float* w1a   = (float*)alloc(TT * 4);
    int*   idxb  = (int*)alloc(EE * CAP * 4);
    float* wslb  = (float*)alloc(EE * CAP * 4);
    int*   fbidx = (int*)alloc(4 * CAP * 4);
    int*   counts = (int*)alloc(64);

    // H buffer: as many experts' worth as workspace allows (21 MB each)
    size_t perExpert = (size_t)CAP * II * 2;
    size_t remain = (ws_size > off) ? (ws_size - off) : 0;
    int G = (int)(remain / perExpert);
    if (G < 1) G = 1;
    if (G > EE) G = EE;
    unsigned short* H = (unsigned short*)(ws + off);

    hipMemsetAsync(d_out, 0, (size_t)TT * DD * sizeof(float), stream);

    cvt_x<<<TT * DD / (256 * 8), 256, 0, stream>>>(x, xbf);
    transpose_cvt<<<dim3(II / 32, DD / 32, EE), dim3(32, 8), 0, stream>>>(W1, W1t, DD, II);
    transpose_cvt<<<dim3(DD / 32, II / 32, EE), dim3(32, 8), 0, stream>>>(W2, W2t, II, DD);
    transpose_cvt<<<dim3(II / 32, DD / 32, 1),  dim3(32, 8), 0, stream>>>(fw1, fw1t, DD, II);
    transpose_cvt<<<dim3(DD / 32, II / 32, 1),  dim3(32, 8), 0, stream>>>(fw2, fw2t, II, DD);

    router_kernel<<<TT / 4, 256, 0, stream>>>(x, Wr, e0a, e1a, w0a, w1a);
    assign_kernel<<<1, 1024, 0, stream>>>(e0a, e1a, w0a, w1a, idxb, wslb, fbidx, counts);

    for (int eb = 0; eb < EE; eb += G) {
        int g = (EE - eb < G) ? (EE - eb) : G;
        gemm_kernel<0><<<dim3(CAP / BM, II / BN, g), 256, 0, stream>>>(
            xbf, W1t, b1, H, nullptr, idxb, wslb, counts, eb, 0);
        gemm_kernel<1><<<dim3(CAP / BM, DD / BN, g), 256, 0, stream>>>(
            H, W2t, b2, nullptr, out, idxb, wslb, counts, eb, 0);
    }
    // fallback FFN over overflow tokens only (n_fb expected 0 -> early exit)
    if (G >= 4) {
        gemm_kernel<2><<<dim3(CAP / BM, II / BN, 4), 256, 0, stream>>>(
            xbf, fw1t, fb1, H, nullptr, fbidx, nullptr, counts, 0, 0);
        gemm_kernel<3><<<dim3(CAP / BM, DD / BN, 4), 256, 0, stream>>>(
            H, fw2t, fb2, nullptr, out, fbidx, nullptr, counts, 0, 0);
    } else {
        for (int c = 0; c < 4; ++c) {
            gemm_kernel<2><<<dim3(CAP / BM, II / BN, 1), 256, 0, stream>>>(
                xbf, fw1t, fb1, H, nullptr, fbidx, nullptr, counts, 0, c * CAP);
            gemm_kernel<3><<<dim3(CAP / BM, DD / BN, 1), 256, 0, stream>>>(
                H, fw2t, fb2, nullptr, out, fbidx, nullptr, counts, 0, c * CAP);
        }
    }
    (void)in_sizes; (void)n_in; (void)out_size;
}